// Round 9
// baseline (830.765 us; speedup 1.0000x reference)
//
#include <hip/hip_runtime.h>

// Problem: x (B=4, C=256, D=32, H=64, W=64) fp32.
// 1) reflect-pad(2) + per-(b,c) mean  == weighted sum over original x
// 2) LSTMCell scan over C=256 channels (B=4, hidden=32, input=1)
// 3) gate[b,c] = sigmoid(h_c . gate_w + gate_b);  out = x * gate[b,c]
//
// R9 = MEASUREMENT ROUND: mean and scale self-replicate (x5 / x4, idempotent)
// so each dispatch outlasts the ~320us harness fills and surfaces in the
// top-5 rocprof rows with its own counters. True durations = dur/reps.
// asm-volatile per rep blocks CSE/DSE (rule #17). Scale uses NORMAL stores
// this round (NT A/B data point).

#define MEAN_DEN (1.0f / 166464.0f)   // 36*68*68
#define MEAN_REPS 5
#define SCALE_REPS 4

typedef unsigned int uint;
typedef float f32x4 __attribute__((ext_vector_type(4)));
typedef float f32x2 __attribute__((ext_vector_type(2)));

__device__ __forceinline__ float sigf(float x) {
    return 1.0f / (1.0f + __expf(-x));
}
__device__ __forceinline__ float tanh_fast(float x) {
    return fmaf(2.0f, sigf(2.0f * x), -1.0f);   // tanh(x) = 2*sigmoid(2x) - 1
}

// ---------- Kernel 1: weighted half-channel partial sums (x MEAN_REPS) ----------
// 2048 blocks (8/CU, 100% occupancy). Block bid: channel bid>>1, half bid&1.
// Accumulator select is compile-time (u literal) - no pointer-to-local.
__global__ __launch_bounds__(256) void mean_kernel(const float* __restrict__ x,
                                                   float* __restrict__ part) {
    const int bid = blockIdx.x;
    const int ch = bid >> 1, half = bid & 1;
    const f32x4* __restrict__ p = (const f32x4*)x + (size_t)ch * 32768 + half * 16384;
    const int base = half * 16384;
    const int tid = threadIdx.x;
    __shared__ float red[256];

    for (int rep = 0; rep < MEAN_REPS; rep++) {
        float s0 = 0.0f, s1 = 0.0f, s2 = 0.0f, s3 = 0.0f;
#pragma unroll
        for (int g = 0; g < 8; g++) {
            f32x4 v[8];
#pragma unroll
            for (int u = 0; u < 8; u++) v[u] = p[g * 2048 + u * 256 + tid];
#pragma unroll
            for (int u = 0; u < 8; u++) {
                const int i = base + g * 2048 + u * 256 + tid;
                const int q = i & 15;             // f4 index within W-row
                const int hh = (i >> 4) & 63;
                const int d = i >> 10;
                float t = (v[u].x + v[u].y) + (v[u].z + v[u].w);
                if (q == 0 || q == 15) t += v[u].y + v[u].z;   // W 1,2,61,62 doubled
                const float wd = ((d == 1) | (d == 2) | (d == 29) | (d == 30)) ? 2.0f : 1.0f;
                const float wh = ((hh == 1) | (hh == 2) | (hh == 61) | (hh == 62)) ? 2.0f : 1.0f;
                const float w = wd * wh;
                if ((u & 3) == 0)      s0 = fmaf(w, t, s0);
                else if ((u & 3) == 1) s1 = fmaf(w, t, s1);
                else if ((u & 3) == 2) s2 = fmaf(w, t, s2);
                else                   s3 = fmaf(w, t, s3);
            }
        }
        float sum = (s0 + s1) + (s2 + s3);
        asm volatile("" : "+v"(sum));     // opaque: block cross-rep CSE/DSE
        __syncthreads();                  // red[] reuse safety across reps
        red[tid] = sum;
        __syncthreads();
        for (int s = 128; s > 0; s >>= 1) {
            if (tid < s) red[tid] += red[tid + s];
            __syncthreads();
        }
        if (tid == 0) part[bid] = red[0];
    }
}

// ---------- Kernel 2: LSTM scan, 4 single-wave blocks (unchanged) ----------
#define RL(v, k) __builtin_bit_cast(float, \
    __builtin_amdgcn_readlane(__builtin_bit_cast(int, (v)), (k)))
#define DW(k) const float w0_##k = W_hh[r0 * 32 + (k)]; \
              const float w1_##k = W_hh[r1 * 32 + (k)];
#define GK(k, A0, A1) { const float hk = RL(h, k); \
                A0 = fmaf(hk, w0_##k, A0); A1 = fmaf(hk, w1_##k, A1); }

__global__ __launch_bounds__(64, 1) void lstm_kernel(
    const float* __restrict__ part,
    const float* __restrict__ W_ih, const float* __restrict__ W_hh,
    const float* __restrict__ b_ih, const float* __restrict__ b_hh,
    const float* __restrict__ gate_w, const float* __restrict__ gate_b,
    float* __restrict__ gates)
{
    __shared__ float cs[256];
    __shared__ float hist[257 * 33];     // stride-33: conflict-free epilogue reads

    const int b = blockIdx.x;            // batch 0..3
    const int l = threadIdx.x;           // lane 0..63
    const int r0 = l, r1 = l + 64;

    const float wih0 = W_ih[r0];
    const float wih1 = W_ih[r1];
    const float bias0 = b_ih[r0] + b_hh[r0];
    const float bias1 = b_ih[r1] + b_hh[r1];
    DW(0)  DW(1)  DW(2)  DW(3)  DW(4)  DW(5)  DW(6)  DW(7)
    DW(8)  DW(9)  DW(10) DW(11) DW(12) DW(13) DW(14) DW(15)
    DW(16) DW(17) DW(18) DW(19) DW(20) DW(21) DW(22) DW(23)
    DW(24) DW(25) DW(26) DW(27) DW(28) DW(29) DW(30) DW(31)

    const f32x2* __restrict__ p2 = (const f32x2*)part + b * 256;
#pragma unroll
    for (int j = 0; j < 4; j++) {
        const int cch = j * 64 + l;
        f32x2 pr = p2[cch];
        cs[cch] = (pr.x + pr.y) * MEAN_DEN;
    }

    float h = 0.0f, cstate = 0.0f;
    for (int t = 0; t < 256; t++) {
        const float inp = cs[t];
        float a0 = fmaf(inp, wih0, bias0), b0 = 0.f, c0 = 0.f, d0 = 0.f;
        float a1 = fmaf(inp, wih1, bias1), b1 = 0.f, c1 = 0.f, d1 = 0.f;
        GK(0,a0,a1)  GK(1,b0,b1)  GK(2,c0,c1)  GK(3,d0,d1)
        GK(4,a0,a1)  GK(5,b0,b1)  GK(6,c0,c1)  GK(7,d0,d1)
        GK(8,a0,a1)  GK(9,b0,b1)  GK(10,c0,c1) GK(11,d0,d1)
        GK(12,a0,a1) GK(13,b0,b1) GK(14,c0,c1) GK(15,d0,d1)
        GK(16,a0,a1) GK(17,b0,b1) GK(18,c0,c1) GK(19,d0,d1)
        GK(20,a0,a1) GK(21,b0,b1) GK(22,c0,c1) GK(23,d0,d1)
        GK(24,a0,a1) GK(25,b0,b1) GK(26,c0,c1) GK(27,d0,d1)
        GK(28,a0,a1) GK(29,b0,b1) GK(30,c0,c1) GK(31,d0,d1)
        const float z0 = (a0 + b0) + (c0 + d0);
        const float z1 = (a1 + b1) + (c1 + d1);
        float zf, zo;
#if __has_builtin(__builtin_amdgcn_permlane32_swap)
        {
            auto ra = __builtin_amdgcn_permlane32_swap(
                __builtin_bit_cast(uint, z0), __builtin_bit_cast(uint, z0), false, false);
            auto rb = __builtin_amdgcn_permlane32_swap(
                __builtin_bit_cast(uint, z1), __builtin_bit_cast(uint, z1), false, false);
            zf = __builtin_bit_cast(float, ra[1]);
            zo = __builtin_bit_cast(float, rb[1]);
        }
#else
        zf = __shfl_xor(z0, 32);
        zo = __shfl_xor(z1, 32);
#endif
        cstate = sigf(zf) * cstate + sigf(z0) * tanh_fast(z1);
        h = sigf(zo) * tanh_fast(cstate);
        if (l < 32) hist[(t + 1) * 33 + l] = h;   // off critical path
    }

    const float gb = gate_b[0];
#pragma unroll
    for (int chunk = 0; chunk < 4; chunk++) {
        const int t = chunk * 64 + l;
        const float* hrow = &hist[(t + 1) * 33];
        float s = gb;
#pragma unroll
        for (int k = 0; k < 32; k++) s = fmaf(hrow[k], gate_w[k], s);
        gates[b * 256 + t] = sigf(s);
    }
}

// ---------- Kernel 3: out = x * gate[ch] (x SCALE_REPS, NORMAL stores) ----------
__global__ __launch_bounds__(256) void scale_kernel(const float* __restrict__ x,
                                                    const float* __restrict__ gates,
                                                    float* __restrict__ out) {
    const int bid = blockIdx.x;
    const int ch = bid >> 1, half = bid & 1;
    const size_t off = (size_t)ch * 32768 + half * 16384;
    const f32x4* __restrict__ xi = (const f32x4*)x + off;
    f32x4* __restrict__ oi = (f32x4*)out + off;
    const int tid = threadIdx.x;

    for (int rep = 0; rep < SCALE_REPS; rep++) {
        float g = gates[ch];
        asm volatile("" : "+v"(g));       // opaque: force full re-execution per rep
#pragma unroll
        for (int gr = 0; gr < 8; gr++) {
            f32x4 v[8];
#pragma unroll
            for (int u = 0; u < 8; u++) v[u] = xi[gr * 2048 + u * 256 + tid];
#pragma unroll
            for (int u = 0; u < 8; u++) {
                v[u] *= g;
                oi[gr * 2048 + u * 256 + tid] = v[u];
            }
        }
    }
}

extern "C" void kernel_launch(void* const* d_in, const int* in_sizes, int n_in,
                              void* d_out, int out_size, void* d_ws, size_t ws_size,
                              hipStream_t stream) {
    const float* x      = (const float*)d_in[0];
    const float* W_ih   = (const float*)d_in[1];   // (128,1)
    const float* W_hh   = (const float*)d_in[2];   // (128,32)
    const float* b_ih   = (const float*)d_in[3];   // (128,)
    const float* b_hh   = (const float*)d_in[4];   // (128,)
    const float* gate_w = (const float*)d_in[5];   // (1,32)
    const float* gate_b = (const float*)d_in[6];   // (1,)
    float* out = (float*)d_out;

    float* part  = (float*)d_ws;          // 2048 floats: half-channel partials
    float* gates = (float*)d_ws + 2048;   // 1024 floats

    mean_kernel<<<2048, 256, 0, stream>>>(x, part);
    lstm_kernel<<<4, 64, 0, stream>>>(part, W_ih, W_hh, b_ih, b_hh,
                                      gate_w, gate_b, gates);
    scale_kernel<<<2048, 256, 0, stream>>>(x, gates, out);
}